// Round 1
// baseline (663.443 us; speedup 1.0000x reference)
//
#include <hip/hip_runtime.h>
#include <math.h>

#define B_ 64
#define T_ 4096
#define D_ 512
#define S_ 32          // T-splits per batch row
#define TS_ (T_ / S_)  // 128 timesteps per block
#define WPT_ (TS_ / 4) // 32 timesteps per wave

// ---------------------------------------------------------------------------
// K1: k = query @ W.T + bias   (k[b,d] = sum_j query[b,j] * W[d,j] + bias[d])
// grid (2, 64): blockIdx.y = b, blockIdx.x selects d-half; 256 threads.
// ---------------------------------------------------------------------------
__global__ __launch_bounds__(256) void key_kernel(const float* __restrict__ query,
                                                  const float* __restrict__ W,
                                                  const float* __restrict__ bias,
                                                  float* __restrict__ k) {
    const int b = blockIdx.y;
    const int d = blockIdx.x * 256 + threadIdx.x;
    __shared__ float4 q[D_ / 4];
    const float4* qrow = (const float4*)(query + (size_t)b * D_);
    if (threadIdx.x < D_ / 4) q[threadIdx.x] = qrow[threadIdx.x];
    __syncthreads();
    const float4* Wd = (const float4*)(W + (size_t)d * D_);
    float acc = bias[d];
#pragma unroll 8
    for (int j = 0; j < D_ / 4; ++j) {
        float4 w4 = Wd[j];
        float4 q4 = q[j];
        acc += q4.x * w4.x + q4.y * w4.y + q4.z * w4.z + q4.w * w4.w;
    }
    k[(size_t)b * D_ + d] = acc;
}

// ---------------------------------------------------------------------------
// K2: fused scores + online softmax + weighted accumulate, one pass over
// attend_to. grid (S_, B_): blockIdx.x = s (t-split), blockIdx.y = b.
// 256 threads = 4 waves; one wave processes one t-row at a time.
// Lane l holds d = {4l..4l+3} and {256+4l..256+4l+3} (two coalesced float4).
// Masked rows (mask[t*B+b] != 0) are skipped entirely -> no HBM fetch.
// ---------------------------------------------------------------------------
__global__ __launch_bounds__(256) void attn_partial_kernel(const float* __restrict__ attend_to,
                                                           const int* __restrict__ mask,
                                                           const float* __restrict__ k,
                                                           float* __restrict__ part_acc,
                                                           float* __restrict__ part_m,
                                                           float* __restrict__ part_l) {
    const int s    = blockIdx.x;
    const int b    = blockIdx.y;
    const int tid  = threadIdx.x;
    const int w    = tid >> 6;   // wave id 0..3
    const int lane = tid & 63;

    const float4* krow = (const float4*)(k + (size_t)b * D_);
    const float4 k0 = krow[lane];
    const float4 k1 = krow[64 + lane];

    float m = -INFINITY;
    float l = 0.0f;
    float4 a0 = make_float4(0.f, 0.f, 0.f, 0.f);
    float4 a1 = make_float4(0.f, 0.f, 0.f, 0.f);

    const int t_base = s * TS_ + w * WPT_;
    for (int i = 0; i < WPT_; ++i) {
        const int t = t_base + i;
        if (mask[t * B_ + b]) continue;  // wave-uniform branch
        const float4* vrow = (const float4*)(attend_to + ((size_t)b * T_ + t) * D_);
        const float4 v0 = vrow[lane];
        const float4 v1 = vrow[64 + lane];
        float p = v0.x * k0.x + v0.y * k0.y + v0.z * k0.z + v0.w * k0.w
                + v1.x * k1.x + v1.y * k1.y + v1.z * k1.z + v1.w * k1.w;
        // 64-lane butterfly reduce -> score broadcast to all lanes
#pragma unroll
        for (int off = 32; off > 0; off >>= 1) p += __shfl_xor(p, off, 64);

        if (p > m) {
            const float alpha = __expf(m - p);  // m=-inf on first hit -> 0
            l *= alpha;
            a0.x *= alpha; a0.y *= alpha; a0.z *= alpha; a0.w *= alpha;
            a1.x *= alpha; a1.y *= alpha; a1.z *= alpha; a1.w *= alpha;
            m = p;
        }
        const float e = __expf(p - m);
        l += e;
        a0.x += e * v0.x; a0.y += e * v0.y; a0.z += e * v0.z; a0.w += e * v0.w;
        a1.x += e * v1.x; a1.y += e * v1.y; a1.z += e * v1.z; a1.w += e * v1.w;
    }

    // combine 4 waves via LDS
    __shared__ float red_acc[4][D_];
    __shared__ float red_m[4];
    __shared__ float red_l[4];
    ((float4*)red_acc[w])[lane]      = a0;
    ((float4*)red_acc[w])[64 + lane] = a1;
    if (lane == 0) { red_m[w] = m; red_l[w] = l; }
    __syncthreads();

    const float m0 = red_m[0], m1 = red_m[1], m2 = red_m[2], m3 = red_m[3];
    const float mb = fmaxf(fmaxf(m0, m1), fmaxf(m2, m3));
    const float s0 = (red_l[0] == 0.f) ? 0.f : __expf(m0 - mb);
    const float s1 = (red_l[1] == 0.f) ? 0.f : __expf(m1 - mb);
    const float s2 = (red_l[2] == 0.f) ? 0.f : __expf(m2 - mb);
    const float s3 = (red_l[3] == 0.f) ? 0.f : __expf(m3 - mb);
    const float lb = red_l[0] * s0 + red_l[1] * s1 + red_l[2] * s2 + red_l[3] * s3;

    const int ps = b * S_ + s;
    float* pa = part_acc + (size_t)ps * D_;
#pragma unroll
    for (int d = tid; d < D_; d += 256) {
        pa[d] = red_acc[0][d] * s0 + red_acc[1][d] * s1 + red_acc[2][d] * s2 + red_acc[3][d] * s3;
    }
    if (tid == 0) { part_m[ps] = mb; part_l[ps] = lb; }
}

// ---------------------------------------------------------------------------
// K3: merge S_ partials per batch row, normalize, write context [B,1,D].
// grid (B_), 256 threads.
// ---------------------------------------------------------------------------
__global__ __launch_bounds__(256) void attn_final_kernel(const float* __restrict__ part_acc,
                                                         const float* __restrict__ part_m,
                                                         const float* __restrict__ part_l,
                                                         float* __restrict__ out) {
    const int b = blockIdx.x;
    const int tid = threadIdx.x;
    __shared__ float sc[S_];

    float mstar = -INFINITY;
#pragma unroll
    for (int s = 0; s < S_; ++s) mstar = fmaxf(mstar, part_m[b * S_ + s]);
    if (tid < S_) {
        const float ls = part_l[b * S_ + tid];
        sc[tid] = (ls == 0.f) ? 0.f : __expf(part_m[b * S_ + tid] - mstar);
    }
    __syncthreads();

    float ltot = 0.f;
#pragma unroll
    for (int s = 0; s < S_; ++s) ltot += part_l[b * S_ + s] * sc[s];
    const float inv = 1.0f / ltot;

#pragma unroll
    for (int d = tid; d < D_; d += 256) {
        float acc = 0.f;
#pragma unroll
        for (int s = 0; s < S_; ++s)
            acc += part_acc[((size_t)(b * S_ + s)) * D_ + d] * sc[s];
        out[(size_t)b * D_ + d] = acc * inv;
    }
}

extern "C" void kernel_launch(void* const* d_in, const int* in_sizes, int n_in,
                              void* d_out, int out_size, void* d_ws, size_t ws_size,
                              hipStream_t stream) {
    const float* query     = (const float*)d_in[0];
    const float* attend_to = (const float*)d_in[1];
    const int*   mask      = (const int*)d_in[2];
    const float* W         = (const float*)d_in[3];
    const float* bias      = (const float*)d_in[4];
    float* out = (float*)d_out;

    float* ws       = (float*)d_ws;
    float* k        = ws;                         // B*D             = 32768 floats
    float* part_acc = k + B_ * D_;                // B*S*D           = 1048576 floats
    float* part_m   = part_acc + B_ * S_ * D_;    // B*S             = 2048 floats
    float* part_l   = part_m + B_ * S_;           // B*S             = 2048 floats
    // total ws: ~4.34 MB

    key_kernel<<<dim3(2, B_), 256, 0, stream>>>(query, W, bias, k);
    attn_partial_kernel<<<dim3(S_, B_), 256, 0, stream>>>(attend_to, mask, k,
                                                          part_acc, part_m, part_l);
    attn_final_kernel<<<dim3(B_), 256, 0, stream>>>(part_acc, part_m, part_l, out);
}

// Round 2
// 661.908 us; speedup vs baseline: 1.0023x; 1.0023x over previous
//
#include <hip/hip_runtime.h>
#include <math.h>

#define B_ 64
#define T_ 4096
#define D_ 512
#define S_ 32          // T-splits per batch row
#define TS_ (T_ / S_)  // 128 timesteps per block
#define WPT_ (TS_ / 4) // 32 timesteps per wave (== ballot bits used)

// ---------------------------------------------------------------------------
// K1: k = query @ W.T + bias   (k[b,d] = sum_j query[b,j] * W[d,j] + bias[d])
// grid (2, 64): blockIdx.y = b, blockIdx.x selects d-half; 256 threads.
// ---------------------------------------------------------------------------
__global__ __launch_bounds__(256) void key_kernel(const float* __restrict__ query,
                                                  const float* __restrict__ W,
                                                  const float* __restrict__ bias,
                                                  float* __restrict__ k) {
    const int b = blockIdx.y;
    const int d = blockIdx.x * 256 + threadIdx.x;
    __shared__ float4 q[D_ / 4];
    const float4* qrow = (const float4*)(query + (size_t)b * D_);
    if (threadIdx.x < D_ / 4) q[threadIdx.x] = qrow[threadIdx.x];
    __syncthreads();
    const float4* Wd = (const float4*)(W + (size_t)d * D_);
    float acc = bias[d];
#pragma unroll 8
    for (int j = 0; j < D_ / 4; ++j) {
        float4 w4 = Wd[j];
        float4 q4 = q[j];
        acc += q4.x * w4.x + q4.y * w4.y + q4.z * w4.z + q4.w * w4.w;
    }
    k[(size_t)b * D_ + d] = acc;
}

// ---------------------------------------------------------------------------
// K2: fused scores + online softmax + weighted accumulate, single pass over
// attend_to. grid (S_, B_). 256 threads = 4 waves; each wave owns 32 t-rows.
// Mask is pre-gathered into a wave-uniform 32-bit ballot (SGPR) so the inner
// loop's control path has NO memory loads -> no vmcnt(0) drain per row.
// Active rows processed in batches of 4: 8 dwordx4 loads in flight, 4
// independent shuffle-reduce chains, one online-softmax update per batch.
// Masked rows are never loaded (saves ~50% of the 512 MB tensor).
// ---------------------------------------------------------------------------
__global__ __launch_bounds__(256) void attn_partial_kernel(const float* __restrict__ attend_to,
                                                           const int* __restrict__ mask,
                                                           const float* __restrict__ k,
                                                           float* __restrict__ part_acc,
                                                           float* __restrict__ part_m,
                                                           float* __restrict__ part_l) {
    const int s    = blockIdx.x;
    const int b    = blockIdx.y;
    const int tid  = threadIdx.x;
    const int w    = tid >> 6;   // wave id 0..3
    const int lane = tid & 63;

    const float4* krow = (const float4*)(k + (size_t)b * D_);
    const float4 k0 = krow[lane];
    const float4 k1 = krow[64 + lane];

    const int t_base = s * TS_ + w * WPT_;
    // lanes 0..31 probe the 32 rows this wave owns; ballot -> uniform SGPR mask
    const int probe_t = t_base + (lane & 31);
    const bool active_lane = (lane < WPT_) && (mask[probe_t * B_ + b] == 0);
    unsigned long long act = __ballot(active_lane);   // bits 0..31 meaningful

    float m = -INFINITY;
    float l = 0.0f;
    float4 a0 = make_float4(0.f, 0.f, 0.f, 0.f);
    float4 a1 = make_float4(0.f, 0.f, 0.f, 0.f);

    const float* rowbase = attend_to + ((size_t)b * T_ + t_base) * D_;

    while (act) {
        // extract up to 4 active row indices (scalar ops, no memory)
        int i0 = __ffsll(act) - 1; act &= act - 1;
        bool h1 = (act != 0);
        int i1 = h1 ? (__ffsll(act) - 1) : i0; act &= act - 1;
        bool h2 = (act != 0);
        int i2 = h2 ? (__ffsll(act) - 1) : i0; act &= act - 1;
        bool h3 = (act != 0);
        int i3 = h3 ? (__ffsll(act) - 1) : i0; act &= act - 1;

        const float4* r0 = (const float4*)(rowbase + (size_t)i0 * D_);
        const float4* r1 = (const float4*)(rowbase + (size_t)i1 * D_);
        const float4* r2 = (const float4*)(rowbase + (size_t)i2 * D_);
        const float4* r3 = (const float4*)(rowbase + (size_t)i3 * D_);
        // 8 dwordx4 loads issued together -> deep MLP
        const float4 v00 = r0[lane], v01 = r0[64 + lane];
        const float4 v10 = r1[lane], v11 = r1[64 + lane];
        const float4 v20 = r2[lane], v21 = r2[64 + lane];
        const float4 v30 = r3[lane], v31 = r3[64 + lane];

        float p0 = v00.x * k0.x + v00.y * k0.y + v00.z * k0.z + v00.w * k0.w
                 + v01.x * k1.x + v01.y * k1.y + v01.z * k1.z + v01.w * k1.w;
        float p1 = v10.x * k0.x + v10.y * k0.y + v10.z * k0.z + v10.w * k0.w
                 + v11.x * k1.x + v11.y * k1.y + v11.z * k1.z + v11.w * k1.w;
        float p2 = v20.x * k0.x + v20.y * k0.y + v20.z * k0.z + v20.w * k0.w
                 + v21.x * k1.x + v21.y * k1.y + v21.z * k1.z + v21.w * k1.w;
        float p3 = v30.x * k0.x + v30.y * k0.y + v30.z * k0.z + v30.w * k0.w
                 + v31.x * k1.x + v31.y * k1.y + v31.z * k1.z + v31.w * k1.w;

        // 4 independent 64-lane butterfly reduces (interleaved for ILP)
#pragma unroll
        for (int off = 32; off > 0; off >>= 1) {
            p0 += __shfl_xor(p0, off, 64);
            p1 += __shfl_xor(p1, off, 64);
            p2 += __shfl_xor(p2, off, 64);
            p3 += __shfl_xor(p3, off, 64);
        }
        if (!h1) p1 = -INFINITY;   // padded duplicates contribute e=0
        if (!h2) p2 = -INFINITY;
        if (!h3) p3 = -INFINITY;

        const float mb = fmaxf(fmaxf(p0, p1), fmaxf(p2, p3));
        if (mb > m) {              // wave-uniform; false only if mb==-inf too
            const float alpha = __expf(m - mb);   // first batch: exp(-inf)=0
            l *= alpha;
            a0.x *= alpha; a0.y *= alpha; a0.z *= alpha; a0.w *= alpha;
            a1.x *= alpha; a1.y *= alpha; a1.z *= alpha; a1.w *= alpha;
            m = mb;
        }
        const float e0 = __expf(p0 - m);
        const float e1 = __expf(p1 - m);
        const float e2 = __expf(p2 - m);
        const float e3 = __expf(p3 - m);
        l += e0 + e1 + e2 + e3;
        a0.x += e0 * v00.x + e1 * v10.x + e2 * v20.x + e3 * v30.x;
        a0.y += e0 * v00.y + e1 * v10.y + e2 * v20.y + e3 * v30.y;
        a0.z += e0 * v00.z + e1 * v10.z + e2 * v20.z + e3 * v30.z;
        a0.w += e0 * v00.w + e1 * v10.w + e2 * v20.w + e3 * v30.w;
        a1.x += e0 * v01.x + e1 * v11.x + e2 * v21.x + e3 * v31.x;
        a1.y += e0 * v01.y + e1 * v11.y + e2 * v21.y + e3 * v31.y;
        a1.z += e0 * v01.z + e1 * v11.z + e2 * v21.z + e3 * v31.z;
        a1.w += e0 * v01.w + e1 * v11.w + e2 * v21.w + e3 * v31.w;
    }

    // combine 4 waves via LDS
    __shared__ float red_acc[4][D_];
    __shared__ float red_m[4];
    __shared__ float red_l[4];
    ((float4*)red_acc[w])[lane]      = a0;
    ((float4*)red_acc[w])[64 + lane] = a1;
    if (lane == 0) { red_m[w] = m; red_l[w] = l; }
    __syncthreads();

    const float m0 = red_m[0], m1 = red_m[1], m2 = red_m[2], m3 = red_m[3];
    const float mb = fmaxf(fmaxf(m0, m1), fmaxf(m2, m3));
    const float s0 = (red_l[0] == 0.f) ? 0.f : __expf(m0 - mb);
    const float s1 = (red_l[1] == 0.f) ? 0.f : __expf(m1 - mb);
    const float s2 = (red_l[2] == 0.f) ? 0.f : __expf(m2 - mb);
    const float s3 = (red_l[3] == 0.f) ? 0.f : __expf(m3 - mb);
    const float lb = red_l[0] * s0 + red_l[1] * s1 + red_l[2] * s2 + red_l[3] * s3;

    const int ps = b * S_ + s;
    float* pa = part_acc + (size_t)ps * D_;
#pragma unroll
    for (int d = tid; d < D_; d += 256) {
        pa[d] = red_acc[0][d] * s0 + red_acc[1][d] * s1 + red_acc[2][d] * s2 + red_acc[3][d] * s3;
    }
    if (tid == 0) { part_m[ps] = mb; part_l[ps] = lb; }
}

// ---------------------------------------------------------------------------
// K3: merge S_ partials per batch row, normalize, write context [B,1,D].
// grid (B_), 256 threads.
// ---------------------------------------------------------------------------
__global__ __launch_bounds__(256) void attn_final_kernel(const float* __restrict__ part_acc,
                                                         const float* __restrict__ part_m,
                                                         const float* __restrict__ part_l,
                                                         float* __restrict__ out) {
    const int b = blockIdx.x;
    const int tid = threadIdx.x;
    __shared__ float sc[S_];

    float mstar = -INFINITY;
#pragma unroll
    for (int s = 0; s < S_; ++s) mstar = fmaxf(mstar, part_m[b * S_ + s]);
    if (tid < S_) {
        const float ls = part_l[b * S_ + tid];
        sc[tid] = (ls == 0.f) ? 0.f : __expf(part_m[b * S_ + tid] - mstar);
    }
    __syncthreads();

    float ltot = 0.f;
#pragma unroll
    for (int s = 0; s < S_; ++s) ltot += part_l[b * S_ + s] * sc[s];
    const float inv = 1.0f / ltot;

#pragma unroll
    for (int d = tid; d < D_; d += 256) {
        float acc = 0.f;
#pragma unroll
        for (int s = 0; s < S_; ++s)
            acc += part_acc[((size_t)(b * S_ + s)) * D_ + d] * sc[s];
        out[(size_t)b * D_ + d] = acc * inv;
    }
}

extern "C" void kernel_launch(void* const* d_in, const int* in_sizes, int n_in,
                              void* d_out, int out_size, void* d_ws, size_t ws_size,
                              hipStream_t stream) {
    const float* query     = (const float*)d_in[0];
    const float* attend_to = (const float*)d_in[1];
    const int*   mask      = (const int*)d_in[2];
    const float* W         = (const float*)d_in[3];
    const float* bias      = (const float*)d_in[4];
    float* out = (float*)d_out;

    float* ws       = (float*)d_ws;
    float* k        = ws;                         // B*D             = 32768 floats
    float* part_acc = k + B_ * D_;                // B*S*D           = 1048576 floats
    float* part_m   = part_acc + B_ * S_ * D_;    // B*S             = 2048 floats
    float* part_l   = part_m + B_ * S_;           // B*S             = 2048 floats

    key_kernel<<<dim3(2, B_), 256, 0, stream>>>(query, W, bias, k);
    attn_partial_kernel<<<dim3(S_, B_), 256, 0, stream>>>(attend_to, mask, k,
                                                          part_acc, part_m, part_l);
    attn_final_kernel<<<dim3(B_), 256, 0, stream>>>(part_acc, part_m, part_l, out);
}